// Round 9
// baseline (1339.547 us; speedup 1.0000x reference)
//
#include <hip/hip_runtime.h>
#include <hip/hip_bf16.h>

#define BSZ   8
#define NPER  8192
#define NNODE 65536       // BSZ*NPER
#define EPG   131072      // edges per graph
#define EMB   128
#define ENCD  512
#define LQ    512
#define NHE   4096
#define NE    1048576
#define NP    1048576
#define NROW  4096        // BSZ*LQ
#define NSPLIT 16
#define SLOT_N 64
#define SLOT_E 384
#define EPART 64          // edge-build partitions per graph (128 nodes each)

typedef _Float16 f16;
typedef _Float16 f16x2 __attribute__((ext_vector_type(2)));
typedef _Float16 f16x4 __attribute__((ext_vector_type(4)));
typedef _Float16 f16x8 __attribute__((ext_vector_type(8)));
typedef float f32x4 __attribute__((ext_vector_type(4)));

// ========== edge CSR: 512 blocks, filtered scan, LDS cursors, no global atomics ==========
__global__ __launch_bounds__(256) void k_edges(const int* __restrict__ eidx,
    int* __restrict__ du, int* __restrict__ cnt_dst, int* __restrict__ csr_dst)
{
  __shared__ int cur[NPER/EPART];    // 128 dst cursors
  __shared__ int duc[NPER/EPART];    // 128 src counters
  const int g  = blockIdx.x & 7;
  const int p  = blockIdx.x >> 3;
  const int lo = p * (NPER/EPART);
  if (threadIdx.x < NPER/EPART){ cur[threadIdx.x] = 0; duc[threadIdx.x] = 0; }
  __syncthreads();
  const int4* srcv = (const int4*)(eidx + g*EPG);
  const int4* dstv = (const int4*)(eidx + NE + g*EPG);
  for (int t = threadIdx.x; t < EPG/4; t += 256){
    int4 s4 = srcv[t];
    int4 d4 = dstv[t];
    int ss[4] = {s4.x, s4.y, s4.z, s4.w};
    int dd[4] = {d4.x, d4.y, d4.z, d4.w};
    #pragma unroll
    for (int u = 0; u < 4; ++u){
      int sl = (ss[u] & (NPER-1)) - lo;
      if ((unsigned)sl < (unsigned)(NPER/EPART)) atomicAdd(&duc[sl], 1);
      int dl = (dd[u] & (NPER-1)) - lo;
      if ((unsigned)dl < (unsigned)(NPER/EPART)){
        int c = atomicAdd(&cur[dl], 1);
        if (c < SLOT_N) csr_dst[(size_t)dd[u]*SLOT_N + c] = ss[u];
      }
    }
  }
  __syncthreads();
  if (threadIdx.x < NPER/EPART){
    int nb = g*NPER + lo + threadIdx.x;
    du[nb]      = duc[threadIdx.x];
    cnt_dst[nb] = cur[threadIdx.x];
  }
}

// ========== hyperedge CSR: global atomic cursors ==========
__global__ __launch_bounds__(256) void k_pairs(const int* __restrict__ hidx,
    int* __restrict__ cnt_pn, int* __restrict__ cnt_pe,
    int* __restrict__ csr_pn, int* __restrict__ csr_pe)
{
  int i = blockIdx.x*256 + threadIdx.x;
  int pn = hidx[2*i], pe = hidx[2*i+1];
  int q1 = atomicAdd(&cnt_pn[pn], 1);
  if (q1 < SLOT_N) csr_pn[pn*SLOT_N + q1] = pe;
  int q2 = atomicAdd(&cnt_pe[pe], 1);
  if (q2 < SLOT_E) csr_pe[pe*SLOT_E + q2] = pn;
}

// ========== nfr16 = f16(nfr * rsqrt(max(du,1))) ==========
__global__ __launch_bounds__(256) void k_pre(const float* __restrict__ nfr,
    const int* __restrict__ du, f16* __restrict__ out)
{
  int i = blockIdx.x*256 + threadIdx.x;         // NNODE*64
  int node = i >> 6, j = i & 63;
  float ds = rsqrtf(fmaxf((float)du[node], 1.f));
  float2 v = ((const float2*)(nfr + (size_t)node*128))[j];
  f16x2 o = { (f16)(v.x*ds), (f16)(v.y*ds) };
  ((f16x2*)(out + (size_t)node*128))[j] = o;
}

// ========== FUSED gconv: gather 32 node-rows (f16 src) -> LDS, GEMM with W (f16 LDS),
// epilogue f16(acc*rsqrt(max(cnt,1)) + bias).  3 blocks/CU (48KB LDS). ==========
__global__ __launch_bounds__(256, 3) void k_gconv(const int* __restrict__ cnt,
    const int* __restrict__ csr, const f16* __restrict__ src,
    const float* __restrict__ W, const float* __restrict__ bias, f16* __restrict__ outp)
{
  __shared__ f16   Wl[128*128];    // 32 KB
  __shared__ float Rl[32*128];     // 16 KB
  const int tid = threadIdx.x;
  const int blk = blockIdx.x;      // NNODE/32 = 2048 blocks, XCD swizzle
  const int nbase = (blk & 7)*NPER + (blk >> 3)*32;
  for (int i = tid; i < 16384; i += 256) Wl[i] = (f16)W[i];
  const int wv = tid >> 6, lane = tid & 63;
  #pragma unroll
  for (int g2 = 0; g2 < 2; ++g2){
    const int nb = nbase + wv*8 + g2*4;
    int c[4]; const int* r[4];
    float ax[4] = {0,0,0,0}, ay[4] = {0,0,0,0};
    #pragma unroll
    for (int u = 0; u < 4; ++u){
      int nd = cnt[nb+u];
      c[u] = nd < SLOT_N ? nd : SLOT_N;
      r[u] = csr + (size_t)(nb+u)*SLOT_N;
    }
    int m = c[0];
    #pragma unroll
    for (int u = 1; u < 4; ++u) m = c[u] > m ? c[u] : m;
    for (int j = 0; j < m; ++j){
      #pragma unroll
      for (int u = 0; u < 4; ++u){
        if (j < c[u]){
          f16x2 v = ((const f16x2*)(src + (size_t)r[u][j]*128))[lane];
          ax[u] += (float)v.x; ay[u] += (float)v.y;
        }
      }
    }
    #pragma unroll
    for (int u = 0; u < 4; ++u)
      ((float2*)&Rl[(wv*8 + g2*4 + u)*128])[lane] = make_float2(ax[u], ay[u]);
  }
  __syncthreads();
  const int c0 = (tid & 31)*4;
  const int r0 = (tid >> 5)*4;
  f32x4 acc[4];
  #pragma unroll
  for (int j = 0; j < 4; ++j) acc[j] = (f32x4){0.f,0.f,0.f,0.f};
  for (int d = 0; d < 128; d += 4){
    f32x4 w[4];
    #pragma unroll
    for (int k = 0; k < 4; ++k){
      f16x4 wh = *(const f16x4*)&Wl[(d+k)*128 + c0];
      w[k] = (f32x4){ (float)wh.x, (float)wh.y, (float)wh.z, (float)wh.w };
    }
    #pragma unroll
    for (int j = 0; j < 4; ++j){
      f32x4 rr = *(const f32x4*)&Rl[(r0+j)*128 + d];
      acc[j] += rr.x*w[0] + rr.y*w[1] + rr.z*w[2] + rr.w*w[3];
    }
  }
  #pragma unroll
  for (int j = 0; j < 4; ++j){
    const int row = nbase + r0 + j;
    float sc = rsqrtf(fmaxf((float)cnt[row], 1.f));
    f16* o = outp + (size_t)row*128 + c0;
    #pragma unroll
    for (int k = 0; k < 4; ++k) o[k] = (f16)(acc[j][k]*sc + bias[c0+k]);
  }
}

// ========== hconv stage 1 (f16 source): ef0[e] = (1/|e|) * sum src16[pn] ==========
__global__ __launch_bounds__(256) void k_hea16(const int* __restrict__ cnt,
    const int* __restrict__ csr, const f16* __restrict__ src, float* __restrict__ ef)
{
  __shared__ float red[4][128];
  int e = blockIdx.x;
  int wv = threadIdx.x >> 6, lane = threadIdx.x & 63;
  int nd = cnt[e];
  int n = nd < SLOT_E ? nd : SLOT_E;
  const int* row = csr + e*SLOT_E;
  float ax = 0.f, ay = 0.f;
  for (int j = wv; j < n; j += 4){
    int p = row[j];
    f16x2 v = ((const f16x2*)(src + (size_t)p*128))[lane];
    ax += (float)v.x; ay += (float)v.y;
  }
  red[wv][lane*2] = ax; red[wv][lane*2+1] = ay;
  __syncthreads();
  if (wv == 0){
    float s = nd > 0 ? 1.f/(float)nd : 0.f;
    float2 o = { (red[0][lane*2]+red[1][lane*2]+red[2][lane*2]+red[3][lane*2])*s,
                 (red[0][lane*2+1]+red[1][lane*2+1]+red[2][lane*2+1]+red[3][lane*2+1])*s };
    ((float2*)(ef + (size_t)e*128))[lane] = o;
  }
}

// ========== register-blocked 128x128 GEMM.  IN16: input rows are f16.
// MODE 0: f32 raw   MODE 2: f16(relu(acc+bias)) ==========
template<int MODE, int IN16>
__global__ __launch_bounds__(256, 2) void k_gemm(const void* __restrict__ inp,
    const float* __restrict__ W, const int* __restrict__ cnt,
    const float* __restrict__ bias, void* __restrict__ outp)
{
  __shared__ float Wl[128*128];
  __shared__ float Rl[32*128];
  const int tid = threadIdx.x;
  const int rbase = blockIdx.x*32;
  for (int i = tid; i < 16384; i += 256) Wl[i] = W[i];
  if (IN16){
    const f16x2* s2 = (const f16x2*)(((const f16*)inp) + (size_t)rbase*128);
    for (int i = tid; i < 2048; i += 256){
      f16x2 v = s2[i];
      ((float2*)Rl)[i] = make_float2((float)v.x, (float)v.y);
    }
  } else {
    const float* src = ((const float*)inp) + (size_t)rbase*128;
    for (int i = tid; i < 4096; i += 256) Rl[i] = src[i];
  }
  __syncthreads();
  const int c0 = (tid & 31)*4;
  const int r0 = (tid >> 5)*4;
  f32x4 acc[4];
  #pragma unroll
  for (int j = 0; j < 4; ++j) acc[j] = (f32x4){0.f,0.f,0.f,0.f};
  for (int d = 0; d < 128; d += 4){
    f32x4 w0 = *(const f32x4*)&Wl[(d+0)*128 + c0];
    f32x4 w1 = *(const f32x4*)&Wl[(d+1)*128 + c0];
    f32x4 w2 = *(const f32x4*)&Wl[(d+2)*128 + c0];
    f32x4 w3 = *(const f32x4*)&Wl[(d+3)*128 + c0];
    #pragma unroll
    for (int j = 0; j < 4; ++j){
      f32x4 rr = *(const f32x4*)&Rl[(r0+j)*128 + d];
      acc[j] += rr.x*w0 + rr.y*w1 + rr.z*w2 + rr.w*w3;
    }
  }
  #pragma unroll
  for (int j = 0; j < 4; ++j){
    const int row = rbase + r0 + j;
    if (MODE == 0){
      *(f32x4*)(((float*)outp) + (size_t)row*128 + c0) = acc[j];
    } else {
      f16* o = ((f16*)outp) + (size_t)row*128 + c0;
      #pragma unroll
      for (int k = 0; k < 4; ++k) o[k] = (f16)fmaxf(acc[j][k] + bias[c0+k], 0.f);
    }
  }
}

// ========== hconv stage 2 + relu + residual, 4 nodes/wave, f16 out.
// PRES: scale by rsqrt(du) (for next layer's prescaled input) ==========
template<int PRES>
__global__ __launch_bounds__(256) void k_nha(const int* __restrict__ cnt,
    const int* __restrict__ csr, const float* __restrict__ ef,
    const float* __restrict__ bias, const float* __restrict__ nfr,
    const int* __restrict__ du, f16* __restrict__ outp)
{
  int wv = threadIdx.x >> 6, lane = threadIdx.x & 63;
  int n0 = blockIdx.x*16 + wv*4;
  int dcnt[4], c[4]; const int* r[4];
  float ax[4] = {0,0,0,0}, ay[4] = {0,0,0,0};
  #pragma unroll
  for (int u = 0; u < 4; ++u){
    dcnt[u] = cnt[n0+u];
    c[u] = dcnt[u] < SLOT_N ? dcnt[u] : SLOT_N;
    r[u] = csr + (size_t)(n0+u)*SLOT_N;
  }
  int m = c[0];
  #pragma unroll
  for (int u = 1; u < 4; ++u) m = c[u] > m ? c[u] : m;
  for (int j = 0; j < m; ++j){
    #pragma unroll
    for (int u = 0; u < 4; ++u){
      if (j < c[u]){
        float2 v = ((const float2*)(ef + (size_t)r[u][j]*128))[lane];
        ax[u] += v.x; ay[u] += v.y;
      }
    }
  }
  float bx = bias[lane*2], by = bias[lane*2+1];
  #pragma unroll
  for (int u = 0; u < 4; ++u){
    float s = dcnt[u] > 0 ? 1.f/(float)dcnt[u] : 0.f;
    float2 nf = ((const float2*)(nfr + (size_t)(n0+u)*128))[lane];
    float vx = fmaxf(ax[u]*s + bx, 0.f) + nf.x;
    float vy = fmaxf(ay[u]*s + by, 0.f) + nf.y;
    float e0 = PRES ? rsqrtf(fmaxf((float)du[n0+u], 1.f)) : 1.f;
    ((f16x2*)(outp + (size_t)(n0+u)*128))[lane] = (f16x2){ (f16)(vx*e0), (f16)(vy*e0) };
  }
}

// ========== q = f16(relu(x @ Wm + bm)), K=512 in 4 LDS chunks ==========
__global__ __launch_bounds__(256) void k_qgemm(const float* __restrict__ x,
    const float* __restrict__ Wm, const float* __restrict__ bm, f16* __restrict__ q)
{
  __shared__ float Wl[128*128];
  const int c = threadIdx.x & 127, rh = threadIdx.x >> 7;
  const int base = blockIdx.x*16 + rh*8;
  float acc[8] = {0,0,0,0,0,0,0,0};
  for (int kc = 0; kc < 4; ++kc){
    __syncthreads();
    for (int i = threadIdx.x; i < 128*128; i += 256) Wl[i] = Wm[kc*128*128 + i];
    __syncthreads();
    #pragma unroll
    for (int r = 0; r < 8; ++r){
      const float* xr = x + (size_t)(base+r)*512 + kc*128;
      float a0=0.f,a1=0.f,a2=0.f,a3=0.f;
      #pragma unroll
      for (int d = 0; d < 128; d += 4){
        a0 += xr[d+0] * Wl[(d+0)*128 + c];
        a1 += xr[d+1] * Wl[(d+1)*128 + c];
        a2 += xr[d+2] * Wl[(d+2)*128 + c];
        a3 += xr[d+3] * Wl[(d+3)*128 + c];
      }
      acc[r] += (a0+a1)+(a2+a3);
    }
  }
  float bv = bm[c];
  #pragma unroll
  for (int r = 0; r < 8; ++r)
    q[(size_t)(base+r)*128 + c] = (f16)fmaxf(acc[r]+bv, 0.f);
}

// ========== gT[b][c][n] = h16[b*NPER+n][c]  (f16 transpose) ==========
__global__ __launch_bounds__(256) void k_gt(const f16* __restrict__ g, f16* __restrict__ gT)
{
  __shared__ f16 t[64][66];
  int b = blockIdx.z, n0 = blockIdx.x*64, c0 = blockIdx.y*64;
  for (int i = threadIdx.x; i < 64*64; i += 256){
    int n = i >> 6, c = i & 63;
    t[n][c] = g[((size_t)(b*NPER + n0 + n))*128 + c0 + c];
  }
  __syncthreads();
  for (int i = threadIdx.x; i < 64*64; i += 256){
    int c = i >> 6, n = i & 63;
    gT[((size_t)(b*128 + c0 + c))*NPER + n0 + n] = t[n][c];
  }
}

// ========== flash attention (R7 config): 64 q-rows/block, n-slab 512, 128-n chunks,
// wave-local P transform, f32 Opart, launch_bounds(256,4) -- NO spills ==========
__global__ __launch_bounds__(256, 4) void k_flash(const f16* __restrict__ qb,
    const f16* __restrict__ kb, const f16* __restrict__ gT,
    float* __restrict__ Opart, float* __restrict__ mZ)
{
  __shared__ f16 Plds[4][16][136];             // per-wave slice
  const int sp = blockIdx.x, l0 = blockIdx.y*64, b = blockIdx.z;
  const int w = threadIdx.x >> 6, lane = threadIdx.x & 63;
  const int quad = lane >> 4, col = lane & 15;
  const int koff = quad*8;
  const f16* qrow = qb + ((size_t)(b*LQ + l0 + w*16 + col))*128 + koff;
  f16x8 aq[4];
  #pragma unroll
  for (int ks = 0; ks < 4; ++ks) aq[ks] = *(const f16x8*)(qrow + ks*32);
  float mrun[4] = {-1e30f,-1e30f,-1e30f,-1e30f};
  float zrun[4] = {0.f,0.f,0.f,0.f};
  f32x4 O[8];
  #pragma unroll
  for (int i = 0; i < 8; ++i) O[i] = (f32x4){0.f,0.f,0.f,0.f};
  const int nbase = sp*(NPER/NSPLIT);          // 512-wide n slab
  #pragma unroll 1
  for (int it = 0; it < (NPER/NSPLIT)/128; ++it){
    const int n0 = nbase + it*128;
    f32x4 st[8];
    #pragma unroll
    for (int t = 0; t < 8; ++t){
      st[t] = (f32x4){0.f,0.f,0.f,0.f};
      const f16* kp = kb + ((size_t)(b*NPER + n0 + t*16 + col))*128 + koff;
      #pragma unroll
      for (int ks = 0; ks < 4; ++ks){
        f16x8 bf = *(const f16x8*)(kp + ks*32);
        st[t] = __builtin_amdgcn_mfma_f32_16x16x32_f16(aq[ks], bf, st[t], 0, 0, 0);
      }
    }
    float alr[4];
    #pragma unroll
    for (int r = 0; r < 4; ++r){
      float rm = st[0][r];
      #pragma unroll
      for (int t = 1; t < 8; ++t) rm = fmaxf(rm, st[t][r]);
      rm = fmaxf(rm, __shfl_xor(rm, 1));
      rm = fmaxf(rm, __shfl_xor(rm, 2));
      rm = fmaxf(rm, __shfl_xor(rm, 4));
      rm = fmaxf(rm, __shfl_xor(rm, 8));
      float mn = fmaxf(mrun[r], rm);
      float al = __expf(mrun[r] - mn);
      float ps[8], rs = 0.f;
      #pragma unroll
      for (int t = 0; t < 8; ++t){ ps[t] = __expf(st[t][r] - mn); rs += ps[t]; }
      rs += __shfl_xor(rs, 1);
      rs += __shfl_xor(rs, 2);
      rs += __shfl_xor(rs, 4);
      rs += __shfl_xor(rs, 8);
      zrun[r] = zrun[r]*al + rs;
      mrun[r] = mn;
      alr[r] = al;
      #pragma unroll
      for (int t = 0; t < 8; ++t) Plds[w][quad*4+r][t*16+col] = (f16)ps[t];
    }
    #pragma unroll
    for (int dt = 0; dt < 8; ++dt)
      #pragma unroll
      for (int r = 0; r < 4; ++r) O[dt][r] *= alr[r];
    __builtin_amdgcn_wave_barrier();
    #pragma unroll
    for (int kk = 0; kk < 4; ++kk){
      f16x8 ap = *(const f16x8*)&Plds[w][col][kk*32 + koff];
      const f16* gv = gT + ((size_t)(b*128 + col))*NPER + n0 + kk*32 + koff;
      #pragma unroll
      for (int dt = 0; dt < 8; ++dt){
        f16x8 bv = *(const f16x8*)(gv + (size_t)dt*16*NPER);
        O[dt] = __builtin_amdgcn_mfma_f32_16x16x32_f16(ap, bv, O[dt], 0, 0, 0);
      }
    }
    __builtin_amdgcn_wave_barrier();
  }
  const int growb = b*LQ + l0 + w*16 + quad*4;
  #pragma unroll
  for (int r = 0; r < 4; ++r){
    float* od = Opart + ((size_t)sp*NROW + growb + r)*128 + col;
    #pragma unroll
    for (int dt = 0; dt < 8; ++dt) od[dt*16] = O[dt][r];
  }
  if (col == 0){
    #pragma unroll
    for (int r = 0; r < 4; ++r){
      ((float2*)mZ)[(size_t)sp*NROW + growb + r] = make_float2(mrun[r], zrun[r]);
    }
  }
}

// ========== combine splits -> Hbuf[row][d] ==========
__global__ __launch_bounds__(256) void k_comb(const float* __restrict__ Opart,
    const float* __restrict__ mZ, float* __restrict__ Hbuf)
{
  int i = blockIdx.x*256 + threadIdx.x;         // NROW*64
  int row = i >> 6, d2 = (i & 63)*2;
  float ms[NSPLIT], zs[NSPLIT];
  float M = -1e30f;
  #pragma unroll
  for (int s = 0; s < NSPLIT; ++s){
    float2 v = ((const float2*)mZ)[(size_t)s*NROW + row];
    ms[s] = v.x; zs[s] = v.y;
    M = fmaxf(M, v.x);
  }
  float Zt = 0.f, ax = 0.f, ay = 0.f;
  #pragma unroll
  for (int s = 0; s < NSPLIT; ++s){
    float e = __expf(ms[s] - M);
    Zt += zs[s]*e;
    const float* op = Opart + ((size_t)s*NROW + row)*128 + d2;
    ax += e*op[0]; ay += e*op[1];
  }
  float inv = 1.f/Zt;
  float* o = Hbuf + (size_t)row*128 + d2;
  o[0] = ax*inv; o[1] = ay*inv;
}

// ========== final: [sigmoid([x,H]@Ws+bs), tanh([x,H]@Wt+bt)] -> f32 ==========
__global__ __launch_bounds__(256) void k_final(const float* __restrict__ x,
    const float* __restrict__ Hbuf,
    const float* __restrict__ Wsg, const float* __restrict__ bsg,
    const float* __restrict__ Wtn, const float* __restrict__ btn,
    float* __restrict__ out)
{
  __shared__ f16 Wl[2*128*128];
  const int c = threadIdx.x;
  const int hsel = c >> 7;
  const int cc = c & 127;
  const int base = blockIdx.x * 16;
  float acc[16];
  #pragma unroll
  for (int r = 0; r < 16; ++r) acc[r] = 0.f;
  for (int kc = 0; kc < 5; ++kc){
    __syncthreads();
    for (int i = threadIdx.x; i < 128*128; i += 256){
      Wl[i]         = (f16)Wsg[kc*16384 + i];
      Wl[16384 + i] = (f16)Wtn[kc*16384 + i];
    }
    __syncthreads();
    const f16* wp = Wl + hsel*16384;
    #pragma unroll
    for (int rg = 0; rg < 4; ++rg){
      const float *cr0, *cr1, *cr2, *cr3;
      if (kc < 4){
        cr0 = x + (size_t)(base + rg*4)*512 + kc*128;
        cr1 = cr0 + 512; cr2 = cr1 + 512; cr3 = cr2 + 512;
      } else {
        cr0 = Hbuf + (size_t)(base + rg*4)*128;
        cr1 = cr0 + 128; cr2 = cr1 + 128; cr3 = cr2 + 128;
      }
      float a0=acc[rg*4], a1=acc[rg*4+1], a2=acc[rg*4+2], a3=acc[rg*4+3];
      #pragma unroll 8
      for (int d = 0; d < 128; ++d){
        float wv = (float)wp[d*128 + cc];
        a0 += cr0[d]*wv; a1 += cr1[d]*wv; a2 += cr2[d]*wv; a3 += cr3[d]*wv;
      }
      acc[rg*4]=a0; acc[rg*4+1]=a1; acc[rg*4+2]=a2; acc[rg*4+3]=a3;
    }
  }
  float bv = hsel ? btn[cc] : bsg[cc];
  #pragma unroll
  for (int r = 0; r < 16; ++r){
    float v = acc[r] + bv;
    v = hsel ? tanhf(v) : 1.f/(1.f + __expf(-v));
    out[(size_t)(base+r)*256 + c] = v;
  }
}

extern "C" void kernel_launch(void* const* d_in, const int* in_sizes, int n_in,
                              void* d_out, int out_size, void* d_ws, size_t ws_size,
                              hipStream_t stream)
{
  const float* x    = (const float*)d_in[0];
  const float* nfr  = (const float*)d_in[1];
  const int*   eidx = (const int*)d_in[2];
  const int*   hidx = (const int*)d_in[3];
  const float *Wg1=(const float*)d_in[4],  *bg1=(const float*)d_in[5];
  const float *Wg2=(const float*)d_in[6],  *bg2=(const float*)d_in[7];
  const float *Wh1=(const float*)d_in[8],  *bh1=(const float*)d_in[9];
  const float *Wh2=(const float*)d_in[10], *bh2=(const float*)d_in[11];
  const float *Wm =(const float*)d_in[12], *bm =(const float*)d_in[13];
  const float *Wm2=(const float*)d_in[14], *bm2=(const float*)d_in[15];
  const float *Wsg=(const float*)d_in[16], *bsg=(const float*)d_in[17];
  const float *Wtn=(const float*)d_in[18], *btn=(const float*)d_in[19];
  float* out = (float*)d_out;

  // ---- workspace layout. Aliases:
  //  h4_16 at base; Hbuf in dead second region; Opart f32 (32MB, NSPLIT16)
  //  aliases dead bufA+bufB; kb/gT alias csr_dst/csr_pn. ----
  char* base = (char*)d_ws;
  f16*   h4_16  = (f16*)(base);                          // 16 MB
  float* Hbuf   = (float*)(base + 33554432);             // 2 MB (dead region)
  f16*   bufA   = (f16*)(base + 67108864);               // 16 MB  (nfr16 / h2_16)
  f16*   bufB   = (f16*)(base + 83886080);               // 16 MB  (h1_16 / h3_16)
  float* Opart  = (float*)(base + 67108864);             // 32 MB  (aliases bufA+bufB)
  int*   csr_dst= (int*)(base + 100663296);              // 16 MB
  f16*   kb     = (f16*)(base + 100663296);              //   (aliases csr_dst)
  int*   csr_pn = (int*)(base + 117440512);              // 16 MB
  f16*   gT     = (f16*)(base + 117440512);              //   (aliases csr_pn)
  int*   csr_pe = (int*)(base + 134217728);              // 6 MB
  int*   cnt_dst= (int*)(base + 140509184);
  int*   cnt_pn = (int*)(base + 140771328);
  int*   cnt_pe = (int*)(base + 141033472);
  int*   du     = (int*)(base + 141049856);
  float* ef0    = (float*)(base + 141312000);            // 2 MB
  float* ef1    = (float*)(base + 143409152);            // 2 MB
  f16*   qb     = (f16*)(base + 145506304);              // 1 MB
  float* mZ     = (float*)(base + 146554880);            // 512 KB (NSPLIT16)
  const size_t needB = (size_t)147079168;
  if (ws_size < needB) return;

  // ---- CSR build ----
  hipMemsetAsync(cnt_pn, 0, 278528, stream);    // cnt_pn + cnt_pe
  k_edges<<<BSZ*EPART, 256, 0, stream>>>(eidx, du, cnt_dst, csr_dst);
  k_pairs<<<NP/256, 256, 0, stream>>>(hidx, cnt_pn, cnt_pe, csr_pn, csr_pe);

  // ---- layer 1 ----
  k_pre<<<NNODE*64/256, 256, 0, stream>>>(nfr, du, bufA);
  k_gconv<<<NNODE/32, 256, 0, stream>>>(cnt_dst, csr_dst, bufA, Wg1, bg1, bufB);
  k_hea16<<<NHE, 256, 0, stream>>>(cnt_pe, csr_pe, bufB, ef0);
  k_gemm<0,0><<<NHE/32, 256, 0, stream>>>(ef0, Wh1, nullptr, nullptr, ef1);
  k_nha<1><<<NNODE/16, 256, 0, stream>>>(cnt_pn, csr_pn, ef1, bh1, nfr, du, bufA);

  // ---- layer 2 ----
  k_gconv<<<NNODE/32, 256, 0, stream>>>(cnt_dst, csr_dst, bufA, Wg2, bg2, bufB);
  k_hea16<<<NHE, 256, 0, stream>>>(cnt_pe, csr_pe, bufB, ef0);
  k_gemm<0,0><<<NHE/32, 256, 0, stream>>>(ef0, Wh2, nullptr, nullptr, ef1);
  k_nha<0><<<NNODE/16, 256, 0, stream>>>(cnt_pn, csr_pn, ef1, bh2, nfr, nullptr, h4_16);

  // ---- attention ----
  k_qgemm<<<NROW/16, 256, 0, stream>>>(x, Wm, bm, qb);
  k_gemm<2,1><<<NNODE/32, 256, 0, stream>>>(h4_16, Wm2, nullptr, bm2, kb);
  k_gt<<<dim3(NPER/64, 2, BSZ), 256, 0, stream>>>(h4_16, gT);
  k_flash<<<dim3(NSPLIT, LQ/64, BSZ), 256, 0, stream>>>(qb, kb, gT, Opart, mZ);
  k_comb<<<NROW*64/256, 256, 0, stream>>>(Opart, mZ, Hbuf);
  k_final<<<NROW/16, 256, 0, stream>>>(x, Hbuf, Wsg, bsg, Wtn, btn, out);

  (void)in_sizes; (void)n_in; (void)out_size;
}

// Round 10
// 1217.452 us; speedup vs baseline: 1.1003x; 1.1003x over previous
//
#include <hip/hip_runtime.h>
#include <hip/hip_bf16.h>

#define BSZ   8
#define NPER  8192
#define NNODE 65536       // BSZ*NPER
#define EPG   131072      // edges per graph
#define EMB   128
#define ENCD  512
#define LQ    512
#define NHE   4096
#define NE    1048576
#define NP    1048576
#define NROW  4096        // BSZ*LQ
#define NSPLIT 16
#define SLOT_N 64
#define SLOT_E 384
#define EPART 64          // edge-build partitions per graph (128 nodes each)

typedef _Float16 f16;
typedef _Float16 f16x2 __attribute__((ext_vector_type(2)));
typedef _Float16 f16x8 __attribute__((ext_vector_type(8)));
typedef float f32x4 __attribute__((ext_vector_type(4)));

// ========== combined CSR build: blocks [0,512) edges (LDS cursors), [512,4608) pairs ==========
__global__ __launch_bounds__(256) void k_build(const int* __restrict__ eidx,
    const int* __restrict__ hidx,
    int* __restrict__ du, int* __restrict__ cnt_dst, int* __restrict__ csr_dst,
    int* __restrict__ cnt_pn, int* __restrict__ cnt_pe,
    int* __restrict__ csr_pn, int* __restrict__ csr_pe)
{
  if (blockIdx.x < BSZ*EPART){
    __shared__ int cur[NPER/EPART];
    __shared__ int duc[NPER/EPART];
    const int g  = blockIdx.x & 7;
    const int p  = blockIdx.x >> 3;
    const int lo = p * (NPER/EPART);
    if (threadIdx.x < NPER/EPART){ cur[threadIdx.x] = 0; duc[threadIdx.x] = 0; }
    __syncthreads();
    const int4* srcv = (const int4*)(eidx + g*EPG);
    const int4* dstv = (const int4*)(eidx + NE + g*EPG);
    for (int t = threadIdx.x; t < EPG/4; t += 256){
      int4 s4 = srcv[t];
      int4 d4 = dstv[t];
      int ss[4] = {s4.x, s4.y, s4.z, s4.w};
      int dd[4] = {d4.x, d4.y, d4.z, d4.w};
      #pragma unroll
      for (int u = 0; u < 4; ++u){
        int sl = (ss[u] & (NPER-1)) - lo;
        if ((unsigned)sl < (unsigned)(NPER/EPART)) atomicAdd(&duc[sl], 1);
        int dl = (dd[u] & (NPER-1)) - lo;
        if ((unsigned)dl < (unsigned)(NPER/EPART)){
          int c = atomicAdd(&cur[dl], 1);
          if (c < SLOT_N) csr_dst[(size_t)dd[u]*SLOT_N + c] = ss[u];
        }
      }
    }
    __syncthreads();
    if (threadIdx.x < NPER/EPART){
      int nb = g*NPER + lo + threadIdx.x;
      du[nb]      = duc[threadIdx.x];
      cnt_dst[nb] = cur[threadIdx.x];
    }
  } else {
    int i = (blockIdx.x - BSZ*EPART)*256 + threadIdx.x;   // covers exactly NP
    int pn = hidx[2*i], pe = hidx[2*i+1];
    int q1 = atomicAdd(&cnt_pn[pn], 1);
    if (q1 < SLOT_N) csr_pn[pn*SLOT_N + q1] = pe;
    int q2 = atomicAdd(&cnt_pe[pe], 1);
    if (q2 < SLOT_E) csr_pe[pe*SLOT_E + q2] = pn;
  }
}

// ========== nfr16 = f16(nfr * rsqrt(max(du,1))) ==========
__global__ __launch_bounds__(256) void k_pre(const float* __restrict__ nfr,
    const int* __restrict__ du, f16* __restrict__ out)
{
  int i = blockIdx.x*256 + threadIdx.x;         // NNODE*64
  int node = i >> 6, j = i & 63;
  float ds = rsqrtf(fmaxf((float)du[node], 1.f));
  float2 v = ((const float2*)(nfr + (size_t)node*128))[j];
  f16x2 o = { (f16)(v.x*ds), (f16)(v.y*ds) };
  ((f16x2*)(out + (size_t)node*128))[j] = o;
}

// ========== gconv gather (f16 src): agg16[d] = f16(sum src16[s]), 4 nodes/wave ==========
__global__ __launch_bounds__(256) void k_gagg16(const int* __restrict__ cnt,
    const int* __restrict__ csr, const f16* __restrict__ src, f16* __restrict__ agg)
{
  int blk  = blockIdx.x;                        // NNODE/16 blocks, XCD swizzle
  int wv = threadIdx.x >> 6, lane = threadIdx.x & 63;
  int n0 = (blk & 7)*NPER + (blk >> 3)*16 + wv*4;
  int c[4]; const int* r[4];
  float ax[4] = {0,0,0,0}, ay[4] = {0,0,0,0};
  #pragma unroll
  for (int u = 0; u < 4; ++u){
    int nd = cnt[n0+u];
    c[u] = nd < SLOT_N ? nd : SLOT_N;
    r[u] = csr + (size_t)(n0+u)*SLOT_N;
  }
  int m = c[0];
  #pragma unroll
  for (int u = 1; u < 4; ++u) m = c[u] > m ? c[u] : m;
  for (int j = 0; j < m; ++j){
    #pragma unroll
    for (int u = 0; u < 4; ++u){
      if (j < c[u]){
        f16x2 v = ((const f16x2*)(src + (size_t)r[u][j]*128))[lane];
        ax[u] += (float)v.x; ay[u] += (float)v.y;
      }
    }
  }
  #pragma unroll
  for (int u = 0; u < 4; ++u)
    ((f16x2*)(agg + (size_t)(n0+u)*128))[lane] = (f16x2){ (f16)ax[u], (f16)ay[u] };
}

// ========== hconv stage 1 (f16 source): ef0[e] = (1/|e|) * sum src16[pn] ==========
__global__ __launch_bounds__(256) void k_hea16(const int* __restrict__ cnt,
    const int* __restrict__ csr, const f16* __restrict__ src, float* __restrict__ ef)
{
  __shared__ float red[4][128];
  int e = blockIdx.x;
  int wv = threadIdx.x >> 6, lane = threadIdx.x & 63;
  int nd = cnt[e];
  int n = nd < SLOT_E ? nd : SLOT_E;
  const int* row = csr + e*SLOT_E;
  float ax = 0.f, ay = 0.f;
  for (int j = wv; j < n; j += 4){
    int p = row[j];
    f16x2 v = ((const f16x2*)(src + (size_t)p*128))[lane];
    ax += (float)v.x; ay += (float)v.y;
  }
  red[wv][lane*2] = ax; red[wv][lane*2+1] = ay;
  __syncthreads();
  if (wv == 0){
    float s = nd > 0 ? 1.f/(float)nd : 0.f;
    float2 o = { (red[0][lane*2]+red[1][lane*2]+red[2][lane*2]+red[3][lane*2])*s,
                 (red[0][lane*2+1]+red[1][lane*2+1]+red[2][lane*2+1]+red[3][lane*2+1])*s };
    ((float2*)(ef + (size_t)e*128))[lane] = o;
  }
}

// ========== register-blocked 128x128 GEMM.  IN16: input rows are f16.
// MODE 0: f32 raw   MODE 1: f16(acc*rsqrt(max(cnt,1)) + bias)   MODE 2: f16(relu(acc+bias)) ==========
template<int MODE, int IN16>
__global__ __launch_bounds__(256, 2) void k_gemm(const void* __restrict__ inp,
    const float* __restrict__ W, const int* __restrict__ cnt,
    const float* __restrict__ bias, void* __restrict__ outp)
{
  __shared__ float Wl[128*128];
  __shared__ float Rl[32*128];
  const int tid = threadIdx.x;
  const int rbase = blockIdx.x*32;
  for (int i = tid; i < 16384; i += 256) Wl[i] = W[i];
  if (IN16){
    const f16x2* s2 = (const f16x2*)(((const f16*)inp) + (size_t)rbase*128);
    for (int i = tid; i < 2048; i += 256){
      f16x2 v = s2[i];
      ((float2*)Rl)[i] = make_float2((float)v.x, (float)v.y);
    }
  } else {
    const float* src = ((const float*)inp) + (size_t)rbase*128;
    for (int i = tid; i < 4096; i += 256) Rl[i] = src[i];
  }
  __syncthreads();
  const int c0 = (tid & 31)*4;
  const int r0 = (tid >> 5)*4;
  f32x4 acc[4];
  #pragma unroll
  for (int j = 0; j < 4; ++j) acc[j] = (f32x4){0.f,0.f,0.f,0.f};
  for (int d = 0; d < 128; d += 4){
    f32x4 w0 = *(const f32x4*)&Wl[(d+0)*128 + c0];
    f32x4 w1 = *(const f32x4*)&Wl[(d+1)*128 + c0];
    f32x4 w2 = *(const f32x4*)&Wl[(d+2)*128 + c0];
    f32x4 w3 = *(const f32x4*)&Wl[(d+3)*128 + c0];
    #pragma unroll
    for (int j = 0; j < 4; ++j){
      f32x4 rr = *(const f32x4*)&Rl[(r0+j)*128 + d];
      acc[j] += rr.x*w0 + rr.y*w1 + rr.z*w2 + rr.w*w3;
    }
  }
  #pragma unroll
  for (int j = 0; j < 4; ++j){
    const int row = rbase + r0 + j;
    if (MODE == 0){
      *(f32x4*)(((float*)outp) + (size_t)row*128 + c0) = acc[j];
    } else if (MODE == 1){
      float sc = rsqrtf(fmaxf((float)cnt[row], 1.f));
      f16* o = ((f16*)outp) + (size_t)row*128 + c0;
      #pragma unroll
      for (int k = 0; k < 4; ++k) o[k] = (f16)(acc[j][k]*sc + bias[c0+k]);
    } else {
      f16* o = ((f16*)outp) + (size_t)row*128 + c0;
      #pragma unroll
      for (int k = 0; k < 4; ++k) o[k] = (f16)fmaxf(acc[j][k] + bias[c0+k], 0.f);
    }
  }
}

// ========== hconv stage 2 + relu + residual, 4 nodes/wave, f16 out.
// PRES: scale by rsqrt(du) (for next layer's prescaled input) ==========
template<int PRES>
__global__ __launch_bounds__(256) void k_nha(const int* __restrict__ cnt,
    const int* __restrict__ csr, const float* __restrict__ ef,
    const float* __restrict__ bias, const float* __restrict__ nfr,
    const int* __restrict__ du, f16* __restrict__ outp)
{
  int wv = threadIdx.x >> 6, lane = threadIdx.x & 63;
  int n0 = blockIdx.x*16 + wv*4;
  int dcnt[4], c[4]; const int* r[4];
  float ax[4] = {0,0,0,0}, ay[4] = {0,0,0,0};
  #pragma unroll
  for (int u = 0; u < 4; ++u){
    dcnt[u] = cnt[n0+u];
    c[u] = dcnt[u] < SLOT_N ? dcnt[u] : SLOT_N;
    r[u] = csr + (size_t)(n0+u)*SLOT_N;
  }
  int m = c[0];
  #pragma unroll
  for (int u = 1; u < 4; ++u) m = c[u] > m ? c[u] : m;
  for (int j = 0; j < m; ++j){
    #pragma unroll
    for (int u = 0; u < 4; ++u){
      if (j < c[u]){
        float2 v = ((const float2*)(ef + (size_t)r[u][j]*128))[lane];
        ax[u] += v.x; ay[u] += v.y;
      }
    }
  }
  float bx = bias[lane*2], by = bias[lane*2+1];
  #pragma unroll
  for (int u = 0; u < 4; ++u){
    float s = dcnt[u] > 0 ? 1.f/(float)dcnt[u] : 0.f;
    float2 nf = ((const float2*)(nfr + (size_t)(n0+u)*128))[lane];
    float vx = fmaxf(ax[u]*s + bx, 0.f) + nf.x;
    float vy = fmaxf(ay[u]*s + by, 0.f) + nf.y;
    float e0 = PRES ? rsqrtf(fmaxf((float)du[n0+u], 1.f)) : 1.f;
    ((f16x2*)(outp + (size_t)(n0+u)*128))[lane] = (f16x2){ (f16)(vx*e0), (f16)(vy*e0) };
  }
}

// ========== q = f16(relu(x @ Wm + bm)), K=512 in 4 LDS chunks ==========
__global__ __launch_bounds__(256) void k_qgemm(const float* __restrict__ x,
    const float* __restrict__ Wm, const float* __restrict__ bm, f16* __restrict__ q)
{
  __shared__ float Wl[128*128];
  const int c = threadIdx.x & 127, rh = threadIdx.x >> 7;
  const int base = blockIdx.x*16 + rh*8;
  float acc[8] = {0,0,0,0,0,0,0,0};
  for (int kc = 0; kc < 4; ++kc){
    __syncthreads();
    for (int i = threadIdx.x; i < 128*128; i += 256) Wl[i] = Wm[kc*128*128 + i];
    __syncthreads();
    #pragma unroll
    for (int r = 0; r < 8; ++r){
      const float* xr = x + (size_t)(base+r)*512 + kc*128;
      float a0=0.f,a1=0.f,a2=0.f,a3=0.f;
      #pragma unroll
      for (int d = 0; d < 128; d += 4){
        a0 += xr[d+0] * Wl[(d+0)*128 + c];
        a1 += xr[d+1] * Wl[(d+1)*128 + c];
        a2 += xr[d+2] * Wl[(d+2)*128 + c];
        a3 += xr[d+3] * Wl[(d+3)*128 + c];
      }
      acc[r] += (a0+a1)+(a2+a3);
    }
  }
  float bv = bm[c];
  #pragma unroll
  for (int r = 0; r < 8; ++r)
    q[(size_t)(base+r)*128 + c] = (f16)fmaxf(acc[r]+bv, 0.f);
}

// ========== gT[b][c][n] = h16[b*NPER+n][c]  (f16 transpose) ==========
__global__ __launch_bounds__(256) void k_gt(const f16* __restrict__ g, f16* __restrict__ gT)
{
  __shared__ f16 t[64][66];
  int b = blockIdx.z, n0 = blockIdx.x*64, c0 = blockIdx.y*64;
  for (int i = threadIdx.x; i < 64*64; i += 256){
    int n = i >> 6, c = i & 63;
    t[n][c] = g[((size_t)(b*NPER + n0 + n))*128 + c0 + c];
  }
  __syncthreads();
  for (int i = threadIdx.x; i < 64*64; i += 256){
    int c = i >> 6, n = i & 63;
    gT[((size_t)(b*128 + c0 + c))*NPER + n0 + n] = t[n][c];
  }
}

// ========== flash attention (R7 config): 64 q-rows/block, n-slab 512, 128-n chunks,
// wave-local P transform, f32 Opart, launch_bounds(256,4) -- no spills ==========
__global__ __launch_bounds__(256, 4) void k_flash(const f16* __restrict__ qb,
    const f16* __restrict__ kb, const f16* __restrict__ gT,
    float* __restrict__ Opart, float* __restrict__ mZ)
{
  __shared__ f16 Plds[4][16][136];             // per-wave slice
  const int sp = blockIdx.x, l0 = blockIdx.y*64, b = blockIdx.z;
  const int w = threadIdx.x >> 6, lane = threadIdx.x & 63;
  const int quad = lane >> 4, col = lane & 15;
  const int koff = quad*8;
  const f16* qrow = qb + ((size_t)(b*LQ + l0 + w*16 + col))*128 + koff;
  f16x8 aq[4];
  #pragma unroll
  for (int ks = 0; ks < 4; ++ks) aq[ks] = *(const f16x8*)(qrow + ks*32);
  float mrun[4] = {-1e30f,-1e30f,-1e30f,-1e30f};
  float zrun[4] = {0.f,0.f,0.f,0.f};
  f32x4 O[8];
  #pragma unroll
  for (int i = 0; i < 8; ++i) O[i] = (f32x4){0.f,0.f,0.f,0.f};
  const int nbase = sp*(NPER/NSPLIT);          // 512-wide n slab
  #pragma unroll 1
  for (int it = 0; it < (NPER/NSPLIT)/128; ++it){
    const int n0 = nbase + it*128;
    f32x4 st[8];
    #pragma unroll
    for (int t = 0; t < 8; ++t){
      st[t] = (f32x4){0.f,0.f,0.f,0.f};
      const f16* kp = kb + ((size_t)(b*NPER + n0 + t*16 + col))*128 + koff;
      #pragma unroll
      for (int ks = 0; ks < 4; ++ks){
        f16x8 bf = *(const f16x8*)(kp + ks*32);
        st[t] = __builtin_amdgcn_mfma_f32_16x16x32_f16(aq[ks], bf, st[t], 0, 0, 0);
      }
    }
    float alr[4];
    #pragma unroll
    for (int r = 0; r < 4; ++r){
      float rm = st[0][r];
      #pragma unroll
      for (int t = 1; t < 8; ++t) rm = fmaxf(rm, st[t][r]);
      rm = fmaxf(rm, __shfl_xor(rm, 1));
      rm = fmaxf(rm, __shfl_xor(rm, 2));
      rm = fmaxf(rm, __shfl_xor(rm, 4));
      rm = fmaxf(rm, __shfl_xor(rm, 8));
      float mn = fmaxf(mrun[r], rm);
      float al = __expf(mrun[r] - mn);
      float ps[8], rs = 0.f;
      #pragma unroll
      for (int t = 0; t < 8; ++t){ ps[t] = __expf(st[t][r] - mn); rs += ps[t]; }
      rs += __shfl_xor(rs, 1);
      rs += __shfl_xor(rs, 2);
      rs += __shfl_xor(rs, 4);
      rs += __shfl_xor(rs, 8);
      zrun[r] = zrun[r]*al + rs;
      mrun[r] = mn;
      alr[r] = al;
      #pragma unroll
      for (int t = 0; t < 8; ++t) Plds[w][quad*4+r][t*16+col] = (f16)ps[t];
    }
    #pragma unroll
    for (int dt = 0; dt < 8; ++dt)
      #pragma unroll
      for (int r = 0; r < 4; ++r) O[dt][r] *= alr[r];
    __builtin_amdgcn_wave_barrier();
    #pragma unroll
    for (int kk = 0; kk < 4; ++kk){
      f16x8 ap = *(const f16x8*)&Plds[w][col][kk*32 + koff];
      const f16* gv = gT + ((size_t)(b*128 + col))*NPER + n0 + kk*32 + koff;
      #pragma unroll
      for (int dt = 0; dt < 8; ++dt){
        f16x8 bv = *(const f16x8*)(gv + (size_t)dt*16*NPER);
        O[dt] = __builtin_amdgcn_mfma_f32_16x16x32_f16(ap, bv, O[dt], 0, 0, 0);
      }
    }
    __builtin_amdgcn_wave_barrier();
  }
  const int growb = b*LQ + l0 + w*16 + quad*4;
  #pragma unroll
  for (int r = 0; r < 4; ++r){
    float* od = Opart + ((size_t)sp*NROW + growb + r)*128 + col;
    #pragma unroll
    for (int dt = 0; dt < 8; ++dt) od[dt*16] = O[dt][r];
  }
  if (col == 0){
    #pragma unroll
    for (int r = 0; r < 4; ++r){
      ((float2*)mZ)[(size_t)sp*NROW + growb + r] = make_float2(mrun[r], zrun[r]);
    }
  }
}

// ========== combine splits -> Hbuf[row][d] ==========
__global__ __launch_bounds__(256) void k_comb(const float* __restrict__ Opart,
    const float* __restrict__ mZ, float* __restrict__ Hbuf)
{
  int i = blockIdx.x*256 + threadIdx.x;         // NROW*64
  int row = i >> 6, d2 = (i & 63)*2;
  float ms[NSPLIT], zs[NSPLIT];
  float M = -1e30f;
  #pragma unroll
  for (int s = 0; s < NSPLIT; ++s){
    float2 v = ((const float2*)mZ)[(size_t)s*NROW + row];
    ms[s] = v.x; zs[s] = v.y;
    M = fmaxf(M, v.x);
  }
  float Zt = 0.f, ax = 0.f, ay = 0.f;
  #pragma unroll
  for (int s = 0; s < NSPLIT; ++s){
    float e = __expf(ms[s] - M);
    Zt += zs[s]*e;
    const float* op = Opart + ((size_t)s*NROW + row)*128 + d2;
    ax += e*op[0]; ay += e*op[1];
  }
  float inv = 1.f/Zt;
  float* o = Hbuf + (size_t)row*128 + d2;
  o[0] = ax*inv; o[1] = ay*inv;
}

// ========== final: [sigmoid([x,H]@Ws+bs), tanh([x,H]@Wt+bt)] -> f32 ==========
__global__ __launch_bounds__(256) void k_final(const float* __restrict__ x,
    const float* __restrict__ Hbuf,
    const float* __restrict__ Wsg, const float* __restrict__ bsg,
    const float* __restrict__ Wtn, const float* __restrict__ btn,
    float* __restrict__ out)
{
  __shared__ f16 Wl[2*128*128];
  const int c = threadIdx.x;
  const int hsel = c >> 7;
  const int cc = c & 127;
  const int base = blockIdx.x * 16;
  float acc[16];
  #pragma unroll
  for (int r = 0; r < 16; ++r) acc[r] = 0.f;
  for (int kc = 0; kc < 5; ++kc){
    __syncthreads();
    for (int i = threadIdx.x; i < 128*128; i += 256){
      Wl[i]         = (f16)Wsg[kc*16384 + i];
      Wl[16384 + i] = (f16)Wtn[kc*16384 + i];
    }
    __syncthreads();
    const f16* wp = Wl + hsel*16384;
    #pragma unroll
    for (int rg = 0; rg < 4; ++rg){
      const float *cr0, *cr1, *cr2, *cr3;
      if (kc < 4){
        cr0 = x + (size_t)(base + rg*4)*512 + kc*128;
        cr1 = cr0 + 512; cr2 = cr1 + 512; cr3 = cr2 + 512;
      } else {
        cr0 = Hbuf + (size_t)(base + rg*4)*128;
        cr1 = cr0 + 128; cr2 = cr1 + 128; cr3 = cr2 + 128;
      }
      float a0=acc[rg*4], a1=acc[rg*4+1], a2=acc[rg*4+2], a3=acc[rg*4+3];
      #pragma unroll 8
      for (int d = 0; d < 128; ++d){
        float wv = (float)wp[d*128 + cc];
        a0 += cr0[d]*wv; a1 += cr1[d]*wv; a2 += cr2[d]*wv; a3 += cr3[d]*wv;
      }
      acc[rg*4]=a0; acc[rg*4+1]=a1; acc[rg*4+2]=a2; acc[rg*4+3]=a3;
    }
  }
  float bv = hsel ? btn[cc] : bsg[cc];
  #pragma unroll
  for (int r = 0; r < 16; ++r){
    float v = acc[r] + bv;
    v = hsel ? tanhf(v) : 1.f/(1.f + __expf(-v));
    out[(size_t)(base+r)*256 + c] = v;
  }
}

extern "C" void kernel_launch(void* const* d_in, const int* in_sizes, int n_in,
                              void* d_out, int out_size, void* d_ws, size_t ws_size,
                              hipStream_t stream)
{
  const float* x    = (const float*)d_in[0];
  const float* nfr  = (const float*)d_in[1];
  const int*   eidx = (const int*)d_in[2];
  const int*   hidx = (const int*)d_in[3];
  const float *Wg1=(const float*)d_in[4],  *bg1=(const float*)d_in[5];
  const float *Wg2=(const float*)d_in[6],  *bg2=(const float*)d_in[7];
  const float *Wh1=(const float*)d_in[8],  *bh1=(const float*)d_in[9];
  const float *Wh2=(const float*)d_in[10], *bh2=(const float*)d_in[11];
  const float *Wm =(const float*)d_in[12], *bm =(const float*)d_in[13];
  const float *Wm2=(const float*)d_in[14], *bm2=(const float*)d_in[15];
  const float *Wsg=(const float*)d_in[16], *bsg=(const float*)d_in[17];
  const float *Wtn=(const float*)d_in[18], *btn=(const float*)d_in[19];
  float* out = (float*)d_out;

  // ---- workspace layout. Aliases:
  //  h4_16 at base; agg16 + Hbuf in second region (both only live when the other's
  //  phase is dead is NOT true for agg16/Hbuf -- they are at distinct offsets);
  //  Opart f32 (32MB, NSPLIT16) aliases dead bufA+bufB; kb/gT alias csr_dst/csr_pn. ----
  char* base = (char*)d_ws;
  f16*   h4_16  = (f16*)(base);                          // 16 MB
  f16*   agg16  = (f16*)(base + 33554432);               // 16 MB (graph phase only)
  float* Hbuf   = (float*)(base + 50331648);             // 2 MB  (attention phase)
  f16*   bufA   = (f16*)(base + 67108864);               // 16 MB  (nfr16 / h2_16)
  f16*   bufB   = (f16*)(base + 83886080);               // 16 MB  (h1_16 / h3_16)
  float* Opart  = (float*)(base + 67108864);             // 32 MB  (aliases bufA+bufB)
  int*   csr_dst= (int*)(base + 100663296);              // 16 MB
  f16*   kb     = (f16*)(base + 100663296);              //   (aliases csr_dst)
  int*   csr_pn = (int*)(base + 117440512);              // 16 MB
  f16*   gT     = (f16*)(base + 117440512);              //   (aliases csr_pn)
  int*   csr_pe = (int*)(base + 134217728);              // 6 MB
  int*   cnt_dst= (int*)(base + 140509184);
  int*   cnt_pn = (int*)(base + 140771328);
  int*   cnt_pe = (int*)(base + 141033472);
  int*   du     = (int*)(base + 141049856);
  float* ef0    = (float*)(base + 141312000);            // 2 MB
  float* ef1    = (float*)(base + 143409152);            // 2 MB
  f16*   qb     = (f16*)(base + 145506304);              // 1 MB
  float* mZ     = (float*)(base + 146554880);            // 512 KB (NSPLIT16)
  const size_t needB = (size_t)147079168;
  if (ws_size < needB) return;

  // ---- CSR build (edges + pairs in one launch) ----
  hipMemsetAsync(cnt_pn, 0, 278528, stream);    // cnt_pn + cnt_pe
  k_build<<<BSZ*EPART + NP/256, 256, 0, stream>>>(eidx, hidx, du, cnt_dst, csr_dst,
                                                  cnt_pn, cnt_pe, csr_pn, csr_pe);

  // ---- layer 1 ----
  k_pre<<<NNODE*64/256, 256, 0, stream>>>(nfr, du, bufA);
  k_gagg16<<<NNODE/16, 256, 0, stream>>>(cnt_dst, csr_dst, bufA, agg16);
  k_gemm<1,1><<<NNODE/32, 256, 0, stream>>>(agg16, Wg1, cnt_dst, bg1, bufB);
  k_hea16<<<NHE, 256, 0, stream>>>(cnt_pe, csr_pe, bufB, ef0);
  k_gemm<0,0><<<NHE/32, 256, 0, stream>>>(ef0, Wh1, nullptr, nullptr, ef1);
  k_nha<1><<<NNODE/16, 256, 0, stream>>>(cnt_pn, csr_pn, ef1, bh1, nfr, du, bufA);

  // ---- layer 2 ----
  k_gagg16<<<NNODE/16, 256, 0, stream>>>(cnt_dst, csr_dst, bufA, agg16);
  k_gemm<1,1><<<NNODE/32, 256, 0, stream>>>(agg16, Wg2, cnt_dst, bg2, bufB);
  k_hea16<<<NHE, 256, 0, stream>>>(cnt_pe, csr_pe, bufB, ef0);
  k_gemm<0,0><<<NHE/32, 256, 0, stream>>>(ef0, Wh2, nullptr, nullptr, ef1);
  k_nha<0><<<NNODE/16, 256, 0, stream>>>(cnt_pn, csr_pn, ef1, bh2, nfr, nullptr, h4_16);

  // ---- attention ----
  k_qgemm<<<NROW/16, 256, 0, stream>>>(x, Wm, bm, qb);
  k_gemm<2,1><<<NNODE/32, 256, 0, stream>>>(h4_16, Wm2, nullptr, bm2, kb);
  k_gt<<<dim3(NPER/64, 2, BSZ), 256, 0, stream>>>(h4_16, gT);
  k_flash<<<dim3(NSPLIT, LQ/64, BSZ), 256, 0, stream>>>(qb, kb, gT, Opart, mZ);
  k_comb<<<NROW*64/256, 256, 0, stream>>>(Opart, mZ, Hbuf);
  k_final<<<NROW/16, 256, 0, stream>>>(x, Hbuf, Wsg, bsg, Wtn, btn, out);

  (void)in_sizes; (void)n_in; (void)out_size;
}